// Round 15
// baseline (73.801 us; speedup 1.0000x reference)
//
#include <hip/hip_runtime.h>
#include <math.h>

#define VOCAB 4096
#define NROWS 65536          // B*L = 4*16384
#define DECAYF 0.99f
#define EPSF 1e-5f

typedef unsigned long long u64;
typedef unsigned int u32;

static __device__ __forceinline__ float min3f(float a, float b, float c) {
    float d; asm("v_min3_f32 %0, %1, %2, %3" : "=v"(d) : "v"(a), "v"(b), "v"(c)); return d;
}

// ---------------- ws layout (bytes) ----------------
// [0,     512)       errpart: 64 doubles (per seg block)
// [2048,  2052)      n value (float)
// [4096,  528384)    keys[NROWS] u64 (monotone dist | cand), 512 KB, memset 0xFF
// [528384, ...)      part[NSEG][VOCAB] float4 (cnt,w0,w1,w2)

// Scan: grid = 512 = 128 row-blocks x 4 table-quarters; block = 512 (8 waves),
// covers 512 rows (lane owns 8 -> ONE broadcast ds_read feeds 8 rows). 16KB
// quarter-table, float4/cand layout (-2x,-2y,-2z,s). Wave scans 128 cands as
// 16 groups of 8: ref-exact dists -> min3 tree -> one strict-< select/group;
// winning group re-derived bit-identically for the exact first-min index.
// Cross-wave merge in aliased LDS; cross-quarter merge via global atomicMin
// on u64 (monotone dist | cand) = exact np.argmin.
// launch_bounds (512,2): VGPR cap 256 -> no spills (R14's (512,4) capped VGPR
// at 64 and spilled: WRITE_SIZE 8MB, 2x VALU stream).
__global__ __launch_bounds__(512, 2) void vq_scan_kernel(
    const float* __restrict__ feats,
    const float* __restrict__ embed,
    u64* __restrict__ keys) {
    #pragma clang fp contract(off)
    __shared__ u64 smem[3584];             // 28 KB: tab (16 KB) + merge scratch
    float4* tab = (float4*)smem;           // 1024 float4

    const int tid  = threadIdx.x;
    const int wave = tid >> 6;
    const int lane = tid & 63;
    const int rblk = blockIdx.x >> 2;
    const int q    = blockIdx.x & 3;
    const int cbase = q << 10;             // 1024 cands per quarter

    // stage quarter-table: thread t stages cands t, t+512
    #pragma unroll
    for (int k = 0; k < 2; ++k) {
        const int c = tid + k * 512;
        const float* e = embed + (cbase + c) * 3;
        const float x = e[0], y = e[1], z = e[2];
        // numpy rounding: (x^2 + y^2) + z^2, each product rounded
        const float s = (x * x + y * y) + z * z;
        tab[c] = make_float4(-2.f * x, -2.f * y, -2.f * z, s);
    }

    // lane's 8 rows: 96 B contiguous = 6x float4
    const int rbase = rblk * 512 + lane * 8;
    const float* fp = feats + rbase * 3;
    const float4 v0 = *(const float4*)(fp +  0);
    const float4 v1 = *(const float4*)(fp +  4);
    const float4 v2 = *(const float4*)(fp +  8);
    const float4 v3 = *(const float4*)(fp + 12);
    const float4 v4 = *(const float4*)(fp + 16);
    const float4 v5 = *(const float4*)(fp + 20);
    const float f0[8] = {v0.x, v0.w, v1.z, v2.y, v3.x, v3.w, v4.z, v5.y};
    const float f1[8] = {v0.y, v1.x, v1.w, v2.z, v3.y, v4.x, v4.w, v5.z};
    const float f2[8] = {v0.z, v1.y, v2.x, v2.w, v3.z, v4.y, v5.x, v5.w};
    float fs[8];
    #pragma unroll
    for (int r = 0; r < 8; ++r)
        fs[r] = (f0[r] * f0[r] + f1[r] * f1[r]) + f2[r] * f2[r];

    __syncthreads();

    float best[8] = {INFINITY, INFINITY, INFINITY, INFINITY,
                     INFINITY, INFINITY, INFINITY, INFINITY};
    int   gb[8]   = {0, 0, 0, 0, 0, 0, 0, 0};   // winning group base (local)
    const float4* __restrict__ wt = tab + (wave << 7);   // 128-cand slice
    const int cw = wave << 7;

    for (int g = 0; g < 16; ++g) {         // 16 groups of 8 cands
        const float4 p0 = wt[8 * g + 0], p1 = wt[8 * g + 1];
        const float4 p2 = wt[8 * g + 2], p3 = wt[8 * g + 3];
        const float4 p4 = wt[8 * g + 4], p5 = wt[8 * g + 5];
        const float4 p6 = wt[8 * g + 6], p7 = wt[8 * g + 7];
        const int lbase = cw + (g << 3);
        #pragma unroll
        for (int r = 0; r < 8; ++r) {
            // ref-exact: d = (fs + fmaf(-2z,f2,fmaf(-2y,f1,(-2x)*f0))) + s
            const float d0 = (fs[r] + fmaf(p0.z, f2[r], fmaf(p0.y, f1[r], p0.x * f0[r]))) + p0.w;
            const float d1 = (fs[r] + fmaf(p1.z, f2[r], fmaf(p1.y, f1[r], p1.x * f0[r]))) + p1.w;
            const float d2 = (fs[r] + fmaf(p2.z, f2[r], fmaf(p2.y, f1[r], p2.x * f0[r]))) + p2.w;
            const float d3 = (fs[r] + fmaf(p3.z, f2[r], fmaf(p3.y, f1[r], p3.x * f0[r]))) + p3.w;
            const float d4 = (fs[r] + fmaf(p4.z, f2[r], fmaf(p4.y, f1[r], p4.x * f0[r]))) + p4.w;
            const float d5 = (fs[r] + fmaf(p5.z, f2[r], fmaf(p5.y, f1[r], p5.x * f0[r]))) + p5.w;
            const float d6 = (fs[r] + fmaf(p6.z, f2[r], fmaf(p6.y, f1[r], p6.x * f0[r]))) + p6.w;
            const float d7 = (fs[r] + fmaf(p7.z, f2[r], fmaf(p7.y, f1[r], p7.x * f0[r]))) + p7.w;
            const float m = min3f(min3f(d0, d1, d2), min3f(d3, d4, d5), fminf(d6, d7));
            if (m < best[r]) { best[r] = m; gb[r] = lbase; }   // strict <
        }
    }

    // ---- recovery: exact first index inside each row's winning group ----
    u64 key[8];
    #pragma unroll
    for (int r = 0; r < 8; ++r) {
        const int b0 = gb[r];
        const float bv = best[r];
        int idx = b0;
        #pragma unroll
        for (int k = 7; k >= 0; --k) {     // descending -> lowest index wins
            const float4 p = tab[b0 + k];
            const float d = (fs[r] + fmaf(p.z, f2[r], fmaf(p.y, f1[r], p.x * f0[r]))) + p.w;
            if (d == bv) idx = b0 + k;     // bit-identical to scan path
        }
        const u32 bb = __float_as_uint(bv);
        const u32 mb = bb ^ ((u32)((int)bb >> 31) | 0x80000000u);   // total order
        key[r] = ((u64)mb << 32) | (u32)(cbase + idx);
    }

    __syncthreads();                       // all waves done reading tab
    // merge scratch (lane-major, conflict-free): waves 1..7 park their keys
    if (wave != 0) {
        #pragma unroll
        for (int r = 0; r < 8; ++r)
            smem[(wave - 1) * 512 + r * 64 + lane] = key[r];
    }
    __syncthreads();
    if (wave == 0) {
        for (int w = 0; w < 7; ++w) {
            #pragma unroll
            for (int r = 0; r < 8; ++r) {
                const u64 k = smem[w * 512 + r * 64 + lane];
                key[r] = k < key[r] ? k : key[r];
            }
        }
        #pragma unroll
        for (int r = 0; r < 8; ++r)
            atomicMin(&keys[rbase + r], key[r]);   // cross-quarter exact merge
    }
}

// Segment sums + expansion. Blocks [0,nseg): per row read merged key -> cand,
// write idx/quant, accumulate err partial, LDS-privatized cnt/wsum partials.
// Block nseg computes n = DECAY*sum(ema_cs) + (1-DECAY)*NROWS.
__global__ __launch_bounds__(1024) void seg_kernel(
    const float* __restrict__ feats,
    const float* __restrict__ embed,
    const u64* __restrict__ keys,
    const float* __restrict__ ema_cs,
    float* __restrict__ quant_out,
    float* __restrict__ idx_out,
    float4* __restrict__ part,
    double* __restrict__ errpart,
    float* __restrict__ n_out,
    int iters, int nseg) {
    #pragma clang fp contract(off)
    __shared__ float lcnt[VOCAB];          // 16 KB
    __shared__ float lw[VOCAB * 3];        // 48 KB
    const int t = threadIdx.x;
    const int b = blockIdx.x;

    if (b == nseg) {                       // n block (input-only reduction)
        float s = ema_cs[t] + ema_cs[t + 1024] + ema_cs[t + 2048] + ema_cs[t + 3072];
        #pragma unroll
        for (int off = 32; off >= 1; off >>= 1) s += __shfl_xor(s, off);
        if ((t & 63) == 0) lcnt[t >> 6] = s;
        __syncthreads();
        if (t == 0) {
            float S = 0.f;
            #pragma unroll
            for (int w = 0; w < 16; ++w) S += lcnt[w];
            *n_out = DECAYF * S + (1.0f - DECAYF) * (float)NROWS;
        }
        return;
    }

    #pragma unroll
    for (int i = 0; i < 4; ++i)  lcnt[t + i * 1024] = 0.0f;
    #pragma unroll
    for (int i = 0; i < 12; ++i) lw[t + i * 1024] = 0.0f;
    __syncthreads();

    float err = 0.0f;
    const int base = b * iters * 1024;
    for (int i = 0; i < iters; ++i) {
        const int row = base + i * 1024 + t;
        const int cand = (int)(u32)keys[row];   // low 32 bits = argmin index

        const float fx = feats[row * 3 + 0];
        const float fy = feats[row * 3 + 1];
        const float fz = feats[row * 3 + 2];

        idx_out[row] = (float)cand;
        const float qx = embed[cand * 3 + 0];   // L2-resident gather
        const float qy = embed[cand * 3 + 1];
        const float qz = embed[cand * 3 + 2];
        quant_out[row * 3 + 0] = qx;
        quant_out[row * 3 + 1] = qy;
        quant_out[row * 3 + 2] = qz;
        const float dx = qx - fx, dy = qy - fy, dz = qz - fz;
        err += dx * dx + dy * dy + dz * dz;

        atomicAdd(&lcnt[cand], 1.0f);
        atomicAdd(&lw[cand * 3 + 0], fx);
        atomicAdd(&lw[cand * 3 + 1], fy);
        atomicAdd(&lw[cand * 3 + 2], fz);
    }
    __syncthreads();

    #pragma unroll
    for (int i = 0; i < 4; ++i) {
        const int v = t + i * 1024;
        part[b * VOCAB + v] = make_float4(lcnt[v], lw[3 * v], lw[3 * v + 1], lw[3 * v + 2]);
    }

    // block err reduce (reuse lcnt after flush)
    __syncthreads();
    #pragma unroll
    for (int off = 32; off >= 1; off >>= 1) err += __shfl_xor(err, off);
    double* ed = (double*)lcnt;            // 16 doubles
    if ((t & 63) == 0) ed[t >> 6] = (double)err;
    __syncthreads();
    if (t == 0) {
        double s = 0.0;
        #pragma unroll
        for (int w = 0; w < 16; ++w) s += ed[w];
        errpart[b] = s;
    }
}

// Reduce partials (ascending b = row-ascending order) + EMA + normalize + loss.
__global__ __launch_bounds__(256) void ema_final_kernel(
    const float4* __restrict__ part,
    const float* __restrict__ ema_cs,
    const float* __restrict__ ema_w,
    const double* __restrict__ errpart,
    const float* __restrict__ n_out,
    float* __restrict__ ncs_out,
    float* __restrict__ nw_out,
    float* __restrict__ embed_out,
    float* __restrict__ loss_out,
    int nseg) {
    const int v = blockIdx.x * 256 + threadIdx.x;
    float c = 0.f, w0 = 0.f, w1 = 0.f, w2 = 0.f;
    for (int b = 0; b < nseg; ++b) {
        const float4 p = part[b * VOCAB + v];
        c += p.x; w0 += p.y; w1 += p.z; w2 += p.w;
    }
    const float ncs = DECAYF * ema_cs[v] + (1.0f - DECAYF) * c;
    const float n0  = DECAYF * ema_w[v * 3 + 0] + (1.0f - DECAYF) * w0;
    const float n1  = DECAYF * ema_w[v * 3 + 1] + (1.0f - DECAYF) * w1;
    const float n2  = DECAYF * ema_w[v * 3 + 2] + (1.0f - DECAYF) * w2;
    ncs_out[v] = ncs;
    nw_out[v * 3 + 0] = n0;
    nw_out[v * 3 + 1] = n1;
    nw_out[v * 3 + 2] = n2;

    const float n = *n_out;
    const float cs = (ncs + EPSF) / (n + (float)VOCAB * EPSF) * n;
    const float d0 = n0 / cs;
    const float d1 = n1 / cs;
    const float d2 = n2 / cs;
    const float nrm = fmaxf(sqrtf(d1 * d1 + d2 * d2), EPSF);
    embed_out[v * 3 + 0] = d0;
    embed_out[v * 3 + 1] = d1 / nrm;
    embed_out[v * 3 + 2] = d2 / nrm;

    if (blockIdx.x == 0) {                 // loss from the nseg err partials
        __shared__ double se[256];
        const int t = threadIdx.x;
        se[t] = (t < nseg) ? errpart[t] : 0.0;
        __syncthreads();
        #pragma unroll
        for (int s = 128; s > 0; s >>= 1) {
            if (t < s) se[t] += se[t + s];
            __syncthreads();
        }
        if (t == 0)
            loss_out[0] = (float)(1.25 * se[0] / (double)(NROWS * 3));
    }
}

extern "C" void kernel_launch(void* const* d_in, const int* in_sizes, int n_in,
                              void* d_out, int out_size, void* d_ws, size_t ws_size,
                              hipStream_t stream) {
    const float* feats  = (const float*)d_in[0];   // 65536*3
    const float* embed  = (const float*)d_in[1];   // 4096*3
    const float* ema_cs = (const float*)d_in[2];   // 4096
    const float* ema_w  = (const float*)d_in[3];   // 4096*3

    float* out = (float*)d_out;
    float* quant_out = out;                         // 196608
    float* idx_out   = out + 196608;                // 65536
    float* loss_out  = out + 262144;                // 1
    float* embed_out = out + 262145;                // 12288
    float* ncs_out   = out + 274433;                // 4096
    float* nw_out    = out + 278529;                // 12288

    char* wsb = (char*)d_ws;
    double* errpart = (double*)wsb;                 // 64 doubles
    float*  n_out   = (float*)(wsb + 2048);         // 1 float
    u64*    keys    = (u64*)(wsb + 4096);           // NROWS u64 = 512 KB
    float4* part    = (float4*)(wsb + 4096 + (size_t)NROWS * 8);

    // NSEG from remaining ws (deterministic)
    const size_t used = 4096 + (size_t)NROWS * 8;
    const size_t per_seg = (size_t)VOCAB * 16;
    const size_t avail = ws_size > used ? ws_size - used : 0;
    int nseg = 2;
    if (avail >= 64 * per_seg)      nseg = 64;
    else if (avail >= 32 * per_seg) nseg = 32;
    else if (avail >= 16 * per_seg) nseg = 16;
    else if (avail >= 8 * per_seg)  nseg = 8;
    else if (avail >= 4 * per_seg)  nseg = 4;
    const int iters = NROWS / (nseg * 1024);

    hipMemsetAsync(keys, 0xFF, (size_t)NROWS * 8, stream);
    vq_scan_kernel<<<512, 512, 0, stream>>>(feats, embed, keys);
    seg_kernel<<<nseg + 1, 1024, 0, stream>>>(feats, embed, keys, ema_cs,
                                              quant_out, idx_out, part,
                                              errpart, n_out, iters, nseg);
    ema_final_kernel<<<VOCAB / 256, 256, 0, stream>>>(part, ema_cs, ema_w,
                                                      errpart, n_out,
                                                      ncs_out, nw_out, embed_out,
                                                      loss_out, nseg);
}

// Round 16
// 65.419 us; speedup vs baseline: 1.1281x; 1.1281x over previous
//
#include <hip/hip_runtime.h>
#include <math.h>

#define VOCAB 4096
#define NROWS 65536          // B*L = 4*16384
#define DECAYF 0.99f
#define EPSF 1e-5f

typedef unsigned long long u64;
typedef unsigned int u32;

static __device__ __forceinline__ float min3f(float a, float b, float c) {
    float d; asm("v_min3_f32 %0, %1, %2, %3" : "=v"(d) : "v"(a), "v"(b), "v"(c)); return d;
}

// ---------------- ws layout (bytes) ----------------
// [0,     512)       errpart: 64 doubles (per seg block)
// [2048,  2052)      n value (float)
// [4096,  4096+2MB)  keys[4][NROWS] u64 (monotone dist | cand), plain writes
// [4096+2MB, ...)    part[NSEG][VOCAB] float4 (cnt,w0,w1,w2)

// Per-row scan step: 8 ref-exact dists -> min3 tree -> one strict-< select.
// ALL per-row state in NAMED SCALARS (no local arrays -> no scratch; R13-R15's
// size-8 arrays defeated SROA: VGPR 48 + 8MB scratch stores).
#define ROW_SCAN(F0, F1, F2, FS, BEST, GB) do {                                        \
    const float d0 = ((FS) + fmaf(p0.z, (F2), fmaf(p0.y, (F1), p0.x * (F0)))) + p0.w;  \
    const float d1 = ((FS) + fmaf(p1.z, (F2), fmaf(p1.y, (F1), p1.x * (F0)))) + p1.w;  \
    const float d2 = ((FS) + fmaf(p2.z, (F2), fmaf(p2.y, (F1), p2.x * (F0)))) + p2.w;  \
    const float d3 = ((FS) + fmaf(p3.z, (F2), fmaf(p3.y, (F1), p3.x * (F0)))) + p3.w;  \
    const float d4 = ((FS) + fmaf(p4.z, (F2), fmaf(p4.y, (F1), p4.x * (F0)))) + p4.w;  \
    const float d5 = ((FS) + fmaf(p5.z, (F2), fmaf(p5.y, (F1), p5.x * (F0)))) + p5.w;  \
    const float d6 = ((FS) + fmaf(p6.z, (F2), fmaf(p6.y, (F1), p6.x * (F0)))) + p6.w;  \
    const float d7 = ((FS) + fmaf(p7.z, (F2), fmaf(p7.y, (F1), p7.x * (F0)))) + p7.w;  \
    const float m = min3f(min3f(d0, d1, d2), min3f(d3, d4, d5), fminf(d6, d7));        \
    if (m < (BEST)) { (BEST) = m; (GB) = lbase; }                                      \
} while (0)

// Recovery: re-read winning group, recompute bit-identically, take first min.
#define ROW_RECOVER(F0, F1, F2, FS, BEST, GB, KEY) do {                                \
    const int b0 = (GB); const float bv = (BEST); int idx = b0;                        \
    _Pragma("unroll")                                                                  \
    for (int k = 7; k >= 0; --k) {                                                     \
        const float4 p = tab[b0 + k];                                                  \
        const float d = ((FS) + fmaf(p.z, (F2), fmaf(p.y, (F1), p.x * (F0)))) + p.w;   \
        if (d == bv) idx = b0 + k;      /* descending k: lowest index wins */          \
    }                                                                                  \
    const u32 bb = __float_as_uint(bv);                                                \
    const u32 mb = bb ^ ((u32)((int)bb >> 31) | 0x80000000u);   /* total order */      \
    (KEY) = ((u64)mb << 32) | (u32)(cbase + idx);                                      \
} while (0)

// Scan: grid = 512 = 128 row-blocks x 4 table-quarters; block = 512 (8 waves),
// covers 512 rows (lane owns 8 -> ONE broadcast ds_read feeds 8 rows). 16KB
// quarter-table (-2x,-2y,-2z,s). Cross-wave merge in aliased LDS; each quarter
// writes a plain key stream; seg merges the 4 streams (u64 min = np.argmin).
__global__ __launch_bounds__(512, 4) void vq_scan_kernel(
    const float* __restrict__ feats,
    const float* __restrict__ embed,
    u64* __restrict__ keys) {
    #pragma clang fp contract(off)
    __shared__ u64 smem[3584];             // 28 KB: tab (16 KB) + merge scratch
    float4* tab = (float4*)smem;           // 1024 float4

    const int tid  = threadIdx.x;
    const int wave = tid >> 6;
    const int lane = tid & 63;
    const int rblk = blockIdx.x >> 2;
    const int q    = blockIdx.x & 3;
    const int cbase = q << 10;             // 1024 cands per quarter

    // stage quarter-table: thread t stages cands t, t+512
    #pragma unroll
    for (int k = 0; k < 2; ++k) {
        const int c = tid + k * 512;
        const float* e = embed + (cbase + c) * 3;
        const float x = e[0], y = e[1], z = e[2];
        // numpy rounding: (x^2 + y^2) + z^2, each product rounded
        const float s = (x * x + y * y) + z * z;
        tab[c] = make_float4(-2.f * x, -2.f * y, -2.f * z, s);
    }

    // lane's 8 rows: 96 B contiguous = 6x float4; all state in named scalars
    const int rbase = rblk * 512 + lane * 8;
    const float* fp = feats + rbase * 3;
    const float4 v0 = *(const float4*)(fp +  0);
    const float4 v1 = *(const float4*)(fp +  4);
    const float4 v2 = *(const float4*)(fp +  8);
    const float4 v3 = *(const float4*)(fp + 12);
    const float4 v4 = *(const float4*)(fp + 16);
    const float4 v5 = *(const float4*)(fp + 20);
    const float f0_0 = v0.x, f1_0 = v0.y, f2_0 = v0.z;
    const float f0_1 = v0.w, f1_1 = v1.x, f2_1 = v1.y;
    const float f0_2 = v1.z, f1_2 = v1.w, f2_2 = v2.x;
    const float f0_3 = v2.y, f1_3 = v2.z, f2_3 = v2.w;
    const float f0_4 = v3.x, f1_4 = v3.y, f2_4 = v3.z;
    const float f0_5 = v3.w, f1_5 = v4.x, f2_5 = v4.y;
    const float f0_6 = v4.z, f1_6 = v4.w, f2_6 = v5.x;
    const float f0_7 = v5.y, f1_7 = v5.z, f2_7 = v5.w;
    const float fs_0 = (f0_0 * f0_0 + f1_0 * f1_0) + f2_0 * f2_0;
    const float fs_1 = (f0_1 * f0_1 + f1_1 * f1_1) + f2_1 * f2_1;
    const float fs_2 = (f0_2 * f0_2 + f1_2 * f1_2) + f2_2 * f2_2;
    const float fs_3 = (f0_3 * f0_3 + f1_3 * f1_3) + f2_3 * f2_3;
    const float fs_4 = (f0_4 * f0_4 + f1_4 * f1_4) + f2_4 * f2_4;
    const float fs_5 = (f0_5 * f0_5 + f1_5 * f1_5) + f2_5 * f2_5;
    const float fs_6 = (f0_6 * f0_6 + f1_6 * f1_6) + f2_6 * f2_6;
    const float fs_7 = (f0_7 * f0_7 + f1_7 * f1_7) + f2_7 * f2_7;

    __syncthreads();

    float best_0 = INFINITY, best_1 = INFINITY, best_2 = INFINITY, best_3 = INFINITY;
    float best_4 = INFINITY, best_5 = INFINITY, best_6 = INFINITY, best_7 = INFINITY;
    int gb_0 = 0, gb_1 = 0, gb_2 = 0, gb_3 = 0, gb_4 = 0, gb_5 = 0, gb_6 = 0, gb_7 = 0;
    const float4* __restrict__ wt = tab + (wave << 7);   // 128-cand slice
    const int cw = wave << 7;

    for (int g = 0; g < 16; ++g) {         // 16 groups of 8 cands
        const float4 p0 = wt[8 * g + 0], p1 = wt[8 * g + 1];
        const float4 p2 = wt[8 * g + 2], p3 = wt[8 * g + 3];
        const float4 p4 = wt[8 * g + 4], p5 = wt[8 * g + 5];
        const float4 p6 = wt[8 * g + 6], p7 = wt[8 * g + 7];
        const int lbase = cw + (g << 3);
        ROW_SCAN(f0_0, f1_0, f2_0, fs_0, best_0, gb_0);
        ROW_SCAN(f0_1, f1_1, f2_1, fs_1, best_1, gb_1);
        ROW_SCAN(f0_2, f1_2, f2_2, fs_2, best_2, gb_2);
        ROW_SCAN(f0_3, f1_3, f2_3, fs_3, best_3, gb_3);
        ROW_SCAN(f0_4, f1_4, f2_4, fs_4, best_4, gb_4);
        ROW_SCAN(f0_5, f1_5, f2_5, fs_5, best_5, gb_5);
        ROW_SCAN(f0_6, f1_6, f2_6, fs_6, best_6, gb_6);
        ROW_SCAN(f0_7, f1_7, f2_7, fs_7, best_7, gb_7);
    }

    u64 key_0, key_1, key_2, key_3, key_4, key_5, key_6, key_7;
    ROW_RECOVER(f0_0, f1_0, f2_0, fs_0, best_0, gb_0, key_0);
    ROW_RECOVER(f0_1, f1_1, f2_1, fs_1, best_1, gb_1, key_1);
    ROW_RECOVER(f0_2, f1_2, f2_2, fs_2, best_2, gb_2, key_2);
    ROW_RECOVER(f0_3, f1_3, f2_3, fs_3, best_3, gb_3, key_3);
    ROW_RECOVER(f0_4, f1_4, f2_4, fs_4, best_4, gb_4, key_4);
    ROW_RECOVER(f0_5, f1_5, f2_5, fs_5, best_5, gb_5, key_5);
    ROW_RECOVER(f0_6, f1_6, f2_6, fs_6, best_6, gb_6, key_6);
    ROW_RECOVER(f0_7, f1_7, f2_7, fs_7, best_7, gb_7, key_7);

    __syncthreads();                       // all waves done reading tab
    if (wave != 0) {                       // lane-major scratch, conflict-free
        u64* mw = smem + (wave - 1) * 512 + lane;
        mw[  0] = key_0; mw[ 64] = key_1; mw[128] = key_2; mw[192] = key_3;
        mw[256] = key_4; mw[320] = key_5; mw[384] = key_6; mw[448] = key_7;
    }
    __syncthreads();
    if (wave == 0) {
        for (int w = 0; w < 7; ++w) {
            const u64* mw = smem + w * 512 + lane;
            u64 k;
            k = mw[  0]; if (k < key_0) key_0 = k;
            k = mw[ 64]; if (k < key_1) key_1 = k;
            k = mw[128]; if (k < key_2) key_2 = k;
            k = mw[192]; if (k < key_3) key_3 = k;
            k = mw[256]; if (k < key_4) key_4 = k;
            k = mw[320]; if (k < key_5) key_5 = k;
            k = mw[384]; if (k < key_6) key_6 = k;
            k = mw[448]; if (k < key_7) key_7 = k;
        }
        u64* kq = keys + (size_t)q * NROWS + rbase;   // plain stream, no init
        kq[0] = key_0; kq[1] = key_1; kq[2] = key_2; kq[3] = key_3;
        kq[4] = key_4; kq[5] = key_5; kq[6] = key_6; kq[7] = key_7;
    }
}

// Segment sums + expansion. Blocks [0,nseg): per row u64-min the 4 quarter
// keys (exact np.argmin), write idx/quant, err partial, LDS-privatized
// cnt/wsum partials. Block nseg computes n = DECAY*sum(ema_cs)+(1-DECAY)*NROWS.
__global__ __launch_bounds__(1024) void seg_kernel(
    const float* __restrict__ feats,
    const float* __restrict__ embed,
    const u64* __restrict__ keys,
    const float* __restrict__ ema_cs,
    float* __restrict__ quant_out,
    float* __restrict__ idx_out,
    float4* __restrict__ part,
    double* __restrict__ errpart,
    float* __restrict__ n_out,
    int iters, int nseg) {
    #pragma clang fp contract(off)
    __shared__ float lcnt[VOCAB];          // 16 KB
    __shared__ float lw[VOCAB * 3];        // 48 KB
    const int t = threadIdx.x;
    const int b = blockIdx.x;

    if (b == nseg) {                       // n block (input-only reduction)
        float s = ema_cs[t] + ema_cs[t + 1024] + ema_cs[t + 2048] + ema_cs[t + 3072];
        #pragma unroll
        for (int off = 32; off >= 1; off >>= 1) s += __shfl_xor(s, off);
        if ((t & 63) == 0) lcnt[t >> 6] = s;
        __syncthreads();
        if (t == 0) {
            float S = 0.f;
            #pragma unroll
            for (int w = 0; w < 16; ++w) S += lcnt[w];
            *n_out = DECAYF * S + (1.0f - DECAYF) * (float)NROWS;
        }
        return;
    }

    #pragma unroll
    for (int i = 0; i < 4; ++i)  lcnt[t + i * 1024] = 0.0f;
    #pragma unroll
    for (int i = 0; i < 12; ++i) lw[t + i * 1024] = 0.0f;
    __syncthreads();

    float err = 0.0f;
    const int base = b * iters * 1024;
    for (int i = 0; i < iters; ++i) {
        const int row = base + i * 1024 + t;
        const u64 k0 = keys[row];
        const u64 k1 = keys[row + NROWS];
        const u64 k2 = keys[row + 2 * NROWS];
        const u64 k3 = keys[row + 3 * NROWS];
        const u64 ka = k0 < k1 ? k0 : k1;
        const u64 kb = k2 < k3 ? k2 : k3;
        const int cand = (int)(u32)(ka < kb ? ka : kb);   // exact np.argmin

        const float fx = feats[row * 3 + 0];
        const float fy = feats[row * 3 + 1];
        const float fz = feats[row * 3 + 2];

        idx_out[row] = (float)cand;
        const float qx = embed[cand * 3 + 0];   // L2-resident gather
        const float qy = embed[cand * 3 + 1];
        const float qz = embed[cand * 3 + 2];
        quant_out[row * 3 + 0] = qx;
        quant_out[row * 3 + 1] = qy;
        quant_out[row * 3 + 2] = qz;
        const float dx = qx - fx, dy = qy - fy, dz = qz - fz;
        err += dx * dx + dy * dy + dz * dz;

        atomicAdd(&lcnt[cand], 1.0f);
        atomicAdd(&lw[cand * 3 + 0], fx);
        atomicAdd(&lw[cand * 3 + 1], fy);
        atomicAdd(&lw[cand * 3 + 2], fz);
    }
    __syncthreads();

    #pragma unroll
    for (int i = 0; i < 4; ++i) {
        const int v = t + i * 1024;
        part[b * VOCAB + v] = make_float4(lcnt[v], lw[3 * v], lw[3 * v + 1], lw[3 * v + 2]);
    }

    // block err reduce (reuse lcnt after flush)
    __syncthreads();
    #pragma unroll
    for (int off = 32; off >= 1; off >>= 1) err += __shfl_xor(err, off);
    double* ed = (double*)lcnt;            // 16 doubles
    if ((t & 63) == 0) ed[t >> 6] = (double)err;
    __syncthreads();
    if (t == 0) {
        double s = 0.0;
        #pragma unroll
        for (int w = 0; w < 16; ++w) s += ed[w];
        errpart[b] = s;
    }
}

// Reduce partials (ascending b = row-ascending order) + EMA + normalize + loss.
__global__ __launch_bounds__(256) void ema_final_kernel(
    const float4* __restrict__ part,
    const float* __restrict__ ema_cs,
    const float* __restrict__ ema_w,
    const double* __restrict__ errpart,
    const float* __restrict__ n_out,
    float* __restrict__ ncs_out,
    float* __restrict__ nw_out,
    float* __restrict__ embed_out,
    float* __restrict__ loss_out,
    int nseg) {
    const int v = blockIdx.x * 256 + threadIdx.x;
    float c = 0.f, w0 = 0.f, w1 = 0.f, w2 = 0.f;
    for (int b = 0; b < nseg; ++b) {
        const float4 p = part[b * VOCAB + v];
        c += p.x; w0 += p.y; w1 += p.z; w2 += p.w;
    }
    const float ncs = DECAYF * ema_cs[v] + (1.0f - DECAYF) * c;
    const float n0  = DECAYF * ema_w[v * 3 + 0] + (1.0f - DECAYF) * w0;
    const float n1  = DECAYF * ema_w[v * 3 + 1] + (1.0f - DECAYF) * w1;
    const float n2  = DECAYF * ema_w[v * 3 + 2] + (1.0f - DECAYF) * w2;
    ncs_out[v] = ncs;
    nw_out[v * 3 + 0] = n0;
    nw_out[v * 3 + 1] = n1;
    nw_out[v * 3 + 2] = n2;

    const float n = *n_out;
    const float cs = (ncs + EPSF) / (n + (float)VOCAB * EPSF) * n;
    const float d0 = n0 / cs;
    const float d1 = n1 / cs;
    const float d2 = n2 / cs;
    const float nrm = fmaxf(sqrtf(d1 * d1 + d2 * d2), EPSF);
    embed_out[v * 3 + 0] = d0;
    embed_out[v * 3 + 1] = d1 / nrm;
    embed_out[v * 3 + 2] = d2 / nrm;

    if (blockIdx.x == 0) {                 // loss from the nseg err partials
        __shared__ double se[256];
        const int t = threadIdx.x;
        se[t] = (t < nseg) ? errpart[t] : 0.0;
        __syncthreads();
        #pragma unroll
        for (int s = 128; s > 0; s >>= 1) {
            if (t < s) se[t] += se[t + s];
            __syncthreads();
        }
        if (t == 0)
            loss_out[0] = (float)(1.25 * se[0] / (double)(NROWS * 3));
    }
}

extern "C" void kernel_launch(void* const* d_in, const int* in_sizes, int n_in,
                              void* d_out, int out_size, void* d_ws, size_t ws_size,
                              hipStream_t stream) {
    const float* feats  = (const float*)d_in[0];   // 65536*3
    const float* embed  = (const float*)d_in[1];   // 4096*3
    const float* ema_cs = (const float*)d_in[2];   // 4096
    const float* ema_w  = (const float*)d_in[3];   // 4096*3

    float* out = (float*)d_out;
    float* quant_out = out;                         // 196608
    float* idx_out   = out + 196608;                // 65536
    float* loss_out  = out + 262144;                // 1
    float* embed_out = out + 262145;                // 12288
    float* ncs_out   = out + 274433;                // 4096
    float* nw_out    = out + 278529;                // 12288

    char* wsb = (char*)d_ws;
    double* errpart = (double*)wsb;                 // 64 doubles
    float*  n_out   = (float*)(wsb + 2048);         // 1 float
    u64*    keys    = (u64*)(wsb + 4096);           // 4*NROWS u64 = 2 MB
    float4* part    = (float4*)(wsb + 4096 + 4 * (size_t)NROWS * 8);

    // NSEG from remaining ws (deterministic)
    const size_t used = 4096 + 4 * (size_t)NROWS * 8;
    const size_t per_seg = (size_t)VOCAB * 16;
    const size_t avail = ws_size > used ? ws_size - used : 0;
    int nseg = 2;
    if (avail >= 64 * per_seg)      nseg = 64;
    else if (avail >= 32 * per_seg) nseg = 32;
    else if (avail >= 16 * per_seg) nseg = 16;
    else if (avail >= 8 * per_seg)  nseg = 8;
    else if (avail >= 4 * per_seg)  nseg = 4;
    const int iters = NROWS / (nseg * 1024);

    vq_scan_kernel<<<512, 512, 0, stream>>>(feats, embed, keys);
    seg_kernel<<<nseg + 1, 1024, 0, stream>>>(feats, embed, keys, ema_cs,
                                              quant_out, idx_out, part,
                                              errpart, n_out, iters, nseg);
    ema_final_kernel<<<VOCAB / 256, 256, 0, stream>>>(part, ema_cs, ema_w,
                                                      errpart, n_out,
                                                      ncs_out, nw_out, embed_out,
                                                      loss_out, nseg);
}

// Round 17
// 64.334 us; speedup vs baseline: 1.1471x; 1.0169x over previous
//
#include <hip/hip_runtime.h>
#include <math.h>

#define VOCAB 4096
#define NROWS 65536          // B*L = 4*16384
#define DECAYF 0.99f
#define EPSF 1e-5f

typedef unsigned long long u64;
typedef unsigned int u32;
typedef float vf2 __attribute__((ext_vector_type(2)));

// ---------------- ws layout (bytes) ----------------
// [0,    2048)  errpart: 256 doubles
// [2048, 2052)  n value (float), written by seg's extra block
// [4096, 4096 + NSEG*VOCAB*16)  part[NSEG][VOCAB] float4 (cnt,w0,w1,w2)

// Scan: block=1024 (16 waves), grid=256. Block packs embed into 64 KB LDS
// pair-transposed (pair p: tab[2p]=(-2x0,-2x1,-2y0,-2y1),
// tab[2p+1]=(-2z0,-2z1,s0,s1)). Lane owns 4 rows; wave scans 256 cands as
// 32 GROUPS of 8: per group 4 dist pairs -> min tree -> ONE strict-<
// select (group base only). Post-scan recovery re-reads the winning group and
// recomputes dists bit-identically to find the exact first-min index
// (= np.argmin tie-break). u64 (monotone dist | idx) cross-wave merge.
__global__ __launch_bounds__(1024, 4) void vq_scan_kernel(
    const float* __restrict__ feats,
    const float* __restrict__ embed,
    float* __restrict__ quant_out,
    float* __restrict__ idx_out,
    double* __restrict__ errpart) {
    #pragma clang fp contract(off)
    __shared__ float4 tab[VOCAB];          // 64 KB; aliased as merge scratch later

    const int tid  = threadIdx.x;
    const int wave = tid >> 6;
    const int lane = tid & 63;

    // stage pair-transposed packed table (thread handles pairs t, t+1024)
    #pragma unroll
    for (int k = 0; k < 2; ++k) {
        const int p = tid + k * 1024;      // pair id 0..2047
        const float* e = embed + p * 6;
        const float x0 = e[0], y0 = e[1], z0 = e[2];
        const float x1 = e[3], y1 = e[4], z1 = e[5];
        // numpy rounding: (x^2 + y^2) + z^2, each product rounded
        const float s0 = (x0 * x0 + y0 * y0) + z0 * z0;
        const float s1 = (x1 * x1 + y1 * y1) + z1 * z1;
        tab[2 * p]     = make_float4(-2.f * x0, -2.f * x1, -2.f * y0, -2.f * y1);
        tab[2 * p + 1] = make_float4(-2.f * z0, -2.f * z1, s0, s1);
    }

    // lane's 4 rows: 48 B contiguous = 3x float4
    const int rbase = blockIdx.x * 256 + lane * 4;
    const float4 fa = *(const float4*)(feats + rbase * 3);
    const float4 fb = *(const float4*)(feats + rbase * 3 + 4);
    const float4 fc = *(const float4*)(feats + rbase * 3 + 8);
    const float f0[4] = {fa.x, fa.w, fb.z, fc.y};
    const float f1[4] = {fa.y, fb.x, fb.w, fc.z};
    const float f2[4] = {fa.z, fb.y, fc.x, fc.w};
    vf2 f0s[4], f1s[4], f2s[4], fss[4];    // loop-invariant splats
    #pragma unroll
    for (int r = 0; r < 4; ++r) {
        const float fs = (f0[r] * f0[r] + f1[r] * f1[r]) + f2[r] * f2[r];
        f0s[r] = (vf2){f0[r], f0[r]};
        f1s[r] = (vf2){f1[r], f1[r]};
        f2s[r] = (vf2){f2[r], f2[r]};
        fss[r] = (vf2){fs, fs};
    }

    __syncthreads();

    float best[4] = {INFINITY, INFINITY, INFINITY, INFINITY};
    int   gb[4]   = {0, 0, 0, 0};          // winning group base (global cand idx)
    const float4* __restrict__ wt = tab + (wave << 8);   // 256 float4 = 256 cands
    const int cw = wave << 8;

    for (int g = 0; g < 32; ++g) {         // 32 groups of 8 cands
        const float4 A0 = wt[8 * g + 0], B0 = wt[8 * g + 1];
        const float4 A1 = wt[8 * g + 2], B1 = wt[8 * g + 3];
        const float4 A2 = wt[8 * g + 4], B2 = wt[8 * g + 5];
        const float4 A3 = wt[8 * g + 6], B3 = wt[8 * g + 7];
        const vf2 xs0 = {A0.x, A0.y}, ys0 = {A0.z, A0.w}, zs0 = {B0.x, B0.y}, es0 = {B0.z, B0.w};
        const vf2 xs1 = {A1.x, A1.y}, ys1 = {A1.z, A1.w}, zs1 = {B1.x, B1.y}, es1 = {B1.z, B1.w};
        const vf2 xs2 = {A2.x, A2.y}, ys2 = {A2.z, A2.w}, zs2 = {B2.x, B2.y}, es2 = {B2.z, B2.w};
        const vf2 xs3 = {A3.x, A3.y}, ys3 = {A3.z, A3.w}, zs3 = {B3.x, B3.y}, es3 = {B3.z, B3.w};
        const int cbase = cw + (g << 3);
        #pragma unroll
        for (int r = 0; r < 4; ++r) {
            // per half: fmaf(z',f2,fmaf(y',f1,x'*f0)); (fs+t)+s  (ref-exact)
            vf2 t0 = __builtin_elementwise_fma(zs0, f2s[r], __builtin_elementwise_fma(ys0, f1s[r], xs0 * f0s[r]));
            vf2 t1 = __builtin_elementwise_fma(zs1, f2s[r], __builtin_elementwise_fma(ys1, f1s[r], xs1 * f0s[r]));
            vf2 t2 = __builtin_elementwise_fma(zs2, f2s[r], __builtin_elementwise_fma(ys2, f1s[r], xs2 * f0s[r]));
            vf2 t3 = __builtin_elementwise_fma(zs3, f2s[r], __builtin_elementwise_fma(ys3, f1s[r], xs3 * f0s[r]));
            vf2 d0 = (fss[r] + t0) + es0;
            vf2 d1 = (fss[r] + t1) + es1;
            vf2 d2 = (fss[r] + t2) + es2;
            vf2 d3 = (fss[r] + t3) + es3;
            vf2 m01 = __builtin_elementwise_min(d0, d1);
            vf2 m23 = __builtin_elementwise_min(d2, d3);
            vf2 m   = __builtin_elementwise_min(m01, m23);
            const float m8 = fminf(m.x, m.y);
            if (m8 < best[r]) { best[r] = m8; gb[r] = cbase; }   // strict <
        }
    }

    // ---- recovery: find exact first index inside each row's winning group ----
    u64 key[4];
    #pragma unroll
    for (int r = 0; r < 4; ++r) {
        const int b0 = gb[r];              // global cand base (also tab index)
        const float bv = best[r];
        int idx = b0;
        #pragma unroll
        for (int k = 3; k >= 0; --k) {     // descending -> lowest index wins
            const float4 A = tab[b0 + 2 * k];
            const float4 B = tab[b0 + 2 * k + 1];
            const vf2 xs = {A.x, A.y}, ys = {A.z, A.w}, zs = {B.x, B.y}, es = {B.z, B.w};
            vf2 t = __builtin_elementwise_fma(zs, f2s[r], __builtin_elementwise_fma(ys, f1s[r], xs * f0s[r]));
            vf2 d = (fss[r] + t) + es;     // bit-identical to scan path
            if (d.y == bv) idx = b0 + 2 * k + 1;
            if (d.x == bv) idx = b0 + 2 * k;
        }
        const u32 bb = __float_as_uint(bv);
        const u32 mb = bb ^ ((u32)((int)bb >> 31) | 0x80000000u);   // total order
        key[r] = ((u64)mb << 32) | (u32)idx;
    }

    __syncthreads();                       // all waves done reading tab
    u64* mk = (u64*)tab;                   // [16][4][64] = 32 KB, aliases tab
    if (wave != 0) {
        #pragma unroll
        for (int r = 0; r < 4; ++r)
            mk[(wave * 4 + r) * 64 + lane] = key[r];
    }
    __syncthreads();
    if (wave == 0) {
        for (int w = 1; w < 16; ++w) {
            #pragma unroll
            for (int r = 0; r < 4; ++r) {
                const u64 k = mk[(w * 4 + r) * 64 + lane];
                key[r] = k < key[r] ? k : key[r];
            }
        }
        int cand[4];
        #pragma unroll
        for (int r = 0; r < 4; ++r) cand[r] = (int)(u32)key[r];

        *(float4*)(idx_out + rbase) =
            make_float4((float)cand[0], (float)cand[1], (float)cand[2], (float)cand[3]);

        float q[4][3];
        #pragma unroll
        for (int r = 0; r < 4; ++r) {
            q[r][0] = embed[cand[r] * 3 + 0];
            q[r][1] = embed[cand[r] * 3 + 1];
            q[r][2] = embed[cand[r] * 3 + 2];
        }
        *(float4*)(quant_out + rbase * 3)     = make_float4(q[0][0], q[0][1], q[0][2], q[1][0]);
        *(float4*)(quant_out + rbase * 3 + 4) = make_float4(q[1][1], q[1][2], q[2][0], q[2][1]);
        *(float4*)(quant_out + rbase * 3 + 8) = make_float4(q[2][2], q[3][0], q[3][1], q[3][2]);

        float err = 0.0f;
        #pragma unroll
        for (int r = 0; r < 4; ++r) {
            const float d0 = q[r][0] - f0[r], d1 = q[r][1] - f1[r], d2 = q[r][2] - f2[r];
            err += d0 * d0 + d1 * d1 + d2 * d2;
        }
        #pragma unroll
        for (int off = 32; off >= 1; off >>= 1) err += __shfl_xor(err, off);
        if (lane == 0) errpart[blockIdx.x] = (double)err;
    }
}

// Segment sums, LDS-privatized; blocks [0,nseg) accumulate partials; the extra
// block (== nseg) computes n = DECAY*sum(ema_cs) + (1-DECAY)*NROWS.
__global__ __launch_bounds__(1024) void seg_kernel(
    const float* __restrict__ feats,
    const float* __restrict__ idx_f,
    const float* __restrict__ ema_cs,
    float4* __restrict__ part,
    float* __restrict__ n_out,
    int iters, int nseg) {
    __shared__ float lcnt[VOCAB];          // 16 KB
    __shared__ float lw[VOCAB * 3];        // 48 KB
    const int t = threadIdx.x;
    const int b = blockIdx.x;

    if (b == nseg) {                       // n block (input-only reduction)
        float s = ema_cs[t] + ema_cs[t + 1024] + ema_cs[t + 2048] + ema_cs[t + 3072];
        #pragma unroll
        for (int off = 32; off >= 1; off >>= 1) s += __shfl_xor(s, off);
        if ((t & 63) == 0) lcnt[t >> 6] = s;
        __syncthreads();
        if (t == 0) {
            float S = 0.f;
            #pragma unroll
            for (int w = 0; w < 16; ++w) S += lcnt[w];
            *n_out = DECAYF * S + (1.0f - DECAYF) * (float)NROWS;
        }
        return;
    }

    #pragma unroll
    for (int i = 0; i < 4; ++i)  lcnt[t + i * 1024] = 0.0f;
    #pragma unroll
    for (int i = 0; i < 12; ++i) lw[t + i * 1024] = 0.0f;
    __syncthreads();

    const int base = b * iters * 1024;
    for (int i = 0; i < iters; ++i) {
        const int row = base + i * 1024 + t;
        const int cand = (int)idx_f[row];
        atomicAdd(&lcnt[cand], 1.0f);
        atomicAdd(&lw[cand * 3 + 0], feats[row * 3 + 0]);
        atomicAdd(&lw[cand * 3 + 1], feats[row * 3 + 1]);
        atomicAdd(&lw[cand * 3 + 2], feats[row * 3 + 2]);
    }
    __syncthreads();

    #pragma unroll
    for (int i = 0; i < 4; ++i) {
        const int v = t + i * 1024;
        part[b * VOCAB + v] = make_float4(lcnt[v], lw[3 * v], lw[3 * v + 1], lw[3 * v + 2]);
    }
}

// Reduce partials (ascending b = row-ascending order) + EMA + normalize + loss.
__global__ __launch_bounds__(256) void ema_final_kernel(
    const float4* __restrict__ part,
    const float* __restrict__ ema_cs,
    const float* __restrict__ ema_w,
    const double* __restrict__ errpart,
    const float* __restrict__ n_out,
    float* __restrict__ ncs_out,
    float* __restrict__ nw_out,
    float* __restrict__ embed_out,
    float* __restrict__ loss_out,
    int nseg) {
    const int v = blockIdx.x * 256 + threadIdx.x;
    float c = 0.f, w0 = 0.f, w1 = 0.f, w2 = 0.f;
    for (int b = 0; b < nseg; ++b) {
        const float4 p = part[b * VOCAB + v];
        c += p.x; w0 += p.y; w1 += p.z; w2 += p.w;
    }
    const float ncs = DECAYF * ema_cs[v] + (1.0f - DECAYF) * c;
    const float n0  = DECAYF * ema_w[v * 3 + 0] + (1.0f - DECAYF) * w0;
    const float n1  = DECAYF * ema_w[v * 3 + 1] + (1.0f - DECAYF) * w1;
    const float n2  = DECAYF * ema_w[v * 3 + 2] + (1.0f - DECAYF) * w2;
    ncs_out[v] = ncs;
    nw_out[v * 3 + 0] = n0;
    nw_out[v * 3 + 1] = n1;
    nw_out[v * 3 + 2] = n2;

    const float n = *n_out;
    const float cs = (ncs + EPSF) / (n + (float)VOCAB * EPSF) * n;
    const float d0 = n0 / cs;
    const float d1 = n1 / cs;
    const float d2 = n2 / cs;
    const float nrm = fmaxf(sqrtf(d1 * d1 + d2 * d2), EPSF);
    embed_out[v * 3 + 0] = d0;
    embed_out[v * 3 + 1] = d1 / nrm;
    embed_out[v * 3 + 2] = d2 / nrm;

    if (blockIdx.x == 0) {                 // loss from the 256 scan partials
        __shared__ double se[256];
        const int t = threadIdx.x;
        se[t] = errpart[t];
        __syncthreads();
        #pragma unroll
        for (int s = 128; s > 0; s >>= 1) {
            if (t < s) se[t] += se[t + s];
            __syncthreads();
        }
        if (t == 0)
            loss_out[0] = (float)(1.25 * se[0] / (double)(NROWS * 3));
    }
}

extern "C" void kernel_launch(void* const* d_in, const int* in_sizes, int n_in,
                              void* d_out, int out_size, void* d_ws, size_t ws_size,
                              hipStream_t stream) {
    const float* feats  = (const float*)d_in[0];   // 65536*3
    const float* embed  = (const float*)d_in[1];   // 4096*3
    const float* ema_cs = (const float*)d_in[2];   // 4096
    const float* ema_w  = (const float*)d_in[3];   // 4096*3

    float* out = (float*)d_out;
    float* quant_out = out;                         // 196608
    float* idx_out   = out + 196608;                // 65536
    float* loss_out  = out + 262144;                // 1
    float* embed_out = out + 262145;                // 12288
    float* ncs_out   = out + 274433;                // 4096
    float* nw_out    = out + 278529;                // 12288

    char* wsb = (char*)d_ws;
    double* errpart = (double*)wsb;                 // 256 doubles
    float*  n_out   = (float*)(wsb + 2048);         // 1 float
    float4* part    = (float4*)(wsb + 4096);        // NSEG*4096 float4

    // NSEG from ws_size (deterministic; 8 proven safe at ~516 KB)
    const size_t per_seg = (size_t)VOCAB * 16;
    const size_t avail = ws_size > 4096 ? ws_size - 4096 : 0;
    int nseg = 8;
    if (avail >= 64 * per_seg)      nseg = 64;
    else if (avail >= 32 * per_seg) nseg = 32;
    else if (avail >= 16 * per_seg) nseg = 16;
    const int iters = NROWS / (nseg * 1024);

    vq_scan_kernel<<<NROWS / 256, 1024, 0, stream>>>(feats, embed,
                                                     quant_out, idx_out, errpart);
    seg_kernel<<<nseg + 1, 1024, 0, stream>>>(feats, idx_out, ema_cs,
                                              part, n_out, iters, nseg);
    ema_final_kernel<<<VOCAB / 256, 256, 0, stream>>>(part, ema_cs, ema_w,
                                                      errpart, n_out,
                                                      ncs_out, nw_out, embed_out,
                                                      loss_out, nseg);
}